// Round 4
// baseline (240.882 us; speedup 1.0000x reference)
//
#include <hip/hip_runtime.h>
#include <math.h>

// tgate_hybrid: B=4,S=4096,DIMS=2048,T=10,K=2.
// R4 structure: 4 rows/lane amortizes the W broadcast LDS reads (the R3
// bottleneck: wave64 ds_read_b128 returns 1024B even on broadcast).
// K1: block = 256 rows x 256 d, 4 waves d-split (64 d each). x staged
//     transposed [d][row] in LDS; W in LDS; per d: 4 x-reads + 8 W-b128
//     feed 120 FMAs. Chunked LDS tree-reduction, wave0 stores partials.
// K2: thread-per-row 64-slice-q reduction + softmax/top2/sigmoid epilogue.

#define NROWS   16384
#define DIMS_   2048
#define TT      10
#define WAVES   4
#define BLOCK   (WAVES * 64)      // 256
#define DGRP    8                 // d-groups (grid.y)
#define DBLK    (DIMS_ / DGRP)    // 256 d per block
#define DPW     (DBLK / WAVES)    // 64 d per wave
#define DC      8                 // d per staged chunk
#define NCH     (DPW / DC)        // 8 chunks
#define RPB     256               // rows per block
#define RPL     4                 // rows per lane

__global__ __launch_bounds__(BLOCK)
void tgate_k1(const float* __restrict__ x,
              const float* __restrict__ W_cls,
              const float* __restrict__ W_sparse,
              const float* __restrict__ W_gates,
              float* __restrict__ ws)
{
    __shared__ float xt[WAVES][DC][RPB];   // 32768 B, transposed x tile (+ red scratch)
    __shared__ float Wl[DBLK * 32];        // 32768 B: [d][cls0..9,sp0..9,g0..9,pad2]

    const int tid  = threadIdx.x;
    const int lane = tid & 63;
    const int wv   = __builtin_amdgcn_readfirstlane(tid >> 6);
    const int row0 = blockIdx.x * RPB;
    const int gy   = blockIdx.y;
    const int d0w  = gy * DBLK + wv * DPW;   // this wave's global d base

    // ---- W preload (coalesced), pads never read
    {
        const float* Wm[3] = { W_cls, W_sparse, W_gates };
        #pragma unroll
        for (int m = 0; m < 3; ++m) {
            const float* src = Wm[m] + (size_t)gy * DBLK * TT;
            #pragma unroll
            for (int it = 0; it < DBLK * TT / BLOCK; ++it) {   // 10 iters
                int f = it * BLOCK + tid;
                int d = f / TT, t = f - d * TT;
                Wl[d * 32 + m * TT + t] = src[f];
            }
        }
    }

    float acc[RPL][TT * 3];
    #pragma unroll
    for (int r = 0; r < RPL; ++r)
        #pragma unroll
        for (int j = 0; j < 30; ++j) acc[r][j] = 0.0f;

    const float4* x4 = reinterpret_cast<const float4*>(x);
    const int rhalf = lane >> 1;        // 0..31: row sub-index for staging
    const int dpart = (lane & 1) * 4;   // 0 or 4: d sub-offset for staging

    float4 pre[8];
    #pragma unroll
    for (int i = 0; i < 8; ++i)
        pre[i] = x4[(size_t)(row0 + i * 32 + rhalf) * (DIMS_ / 4) + ((d0w + dpart) >> 2)];

    __syncthreads();   // Wl ready

    for (int c = 0; c < NCH; ++c) {
        // stage transposed: xt[wv][d][row]  (2-way bank alias = free)
        #pragma unroll
        for (int i = 0; i < 8; ++i) {
            int rl = i * 32 + rhalf;
            xt[wv][dpart + 0][rl] = pre[i].x;
            xt[wv][dpart + 1][rl] = pre[i].y;
            xt[wv][dpart + 2][rl] = pre[i].z;
            xt[wv][dpart + 3][rl] = pre[i].w;
        }
        if (c + 1 < NCH) {
            #pragma unroll
            for (int i = 0; i < 8; ++i)
                pre[i] = x4[(size_t)(row0 + i * 32 + rhalf) * (DIMS_ / 4)
                            + ((d0w + (c + 1) * DC + dpart) >> 2)];
        }
        const int dl0 = wv * DPW + c * DC;   // block-local d of chunk start
        #pragma unroll
        for (int dd = 0; dd < DC; ++dd) {
            float xv[RPL];
            #pragma unroll
            for (int r = 0; r < RPL; ++r) xv[r] = xt[wv][dd][lane + 64 * r];
            const float4* wr = reinterpret_cast<const float4*>(&Wl[(dl0 + dd) * 32]);
            #pragma unroll
            for (int q = 0; q < 8; ++q) {
                float4 w = wr[q];
                #pragma unroll
                for (int r = 0; r < RPL; ++r) {
                    if (q * 4 + 0 < 30) acc[r][q * 4 + 0] = fmaf(xv[r], w.x, acc[r][q * 4 + 0]);
                    if (q * 4 + 1 < 30) acc[r][q * 4 + 1] = fmaf(xv[r], w.y, acc[r][q * 4 + 1]);
                    if (q * 4 + 2 < 30) acc[r][q * 4 + 2] = fmaf(xv[r], w.z, acc[r][q * 4 + 2]);
                    if (q * 4 + 3 < 30) acc[r][q * 4 + 3] = fmaf(xv[r], w.w, acc[r][q * 4 + 3]);
                }
            }
        }
    }

    // ---- cross-wave reduction, chunked over q-pairs, reusing xt as scratch
    float* red = &xt[0][0][0];   // need 32*192 floats = 24 KB <= 32 KB
    __syncthreads();             // all compute done
    for (int p = 0; p < 4; ++p) {          // q = 2p, 2p+1
        if (wv > 0) {
            int widx = (wv - 1) * 64 + lane;
            #pragma unroll
            for (int qq = 0; qq < 2; ++qq)
                #pragma unroll
                for (int r = 0; r < RPL; ++r)
                    #pragma unroll
                    for (int cm = 0; cm < 4; ++cm) {
                        int t = (2 * p + qq) * 4 + cm;
                        float v = (t < 30) ? acc[r][t] : 0.0f;
                        red[((qq * 4 + r) * 4 + cm) * 192 + widx] = v;
                    }
        }
        __syncthreads();
        if (wv == 0) {
            #pragma unroll
            for (int qq = 0; qq < 2; ++qq)
                #pragma unroll
                for (int r = 0; r < RPL; ++r)
                    #pragma unroll
                    for (int cm = 0; cm < 4; ++cm) {
                        int t = (2 * p + qq) * 4 + cm;
                        if (t < 30) {
                            float s = acc[r][t];
                            #pragma unroll
                            for (int w = 1; w < WAVES; ++w)
                                s += red[((qq * 4 + r) * 4 + cm) * 192 + (w - 1) * 64 + lane];
                            acc[r][t] = s;
                        }
                    }
        }
        __syncthreads();
    }

    // ---- wave 0 stores partials: ws4[(gy*8+q)*NROWS + row], coalesced
    if (wv == 0) {
        float4* ws4 = reinterpret_cast<float4*>(ws);
        #pragma unroll
        for (int q = 0; q < 8; ++q)
            #pragma unroll
            for (int r = 0; r < RPL; ++r) {
                float a0 = acc[r][q * 4 + 0];
                float a1 = acc[r][q * 4 + 1];
                float a2 = (q * 4 + 2 < 30) ? acc[r][q * 4 + 2] : 0.0f;
                float a3 = (q * 4 + 3 < 30) ? acc[r][q * 4 + 3] : 0.0f;
                ws4[(size_t)(gy * 8 + q) * NROWS + row0 + 64 * r + lane] =
                    make_float4(a0, a1, a2, a3);
            }
    }
}

__global__ __launch_bounds__(256)
void tgate_k2(const float* __restrict__ ws,
              const float* __restrict__ b_cls,
              const float* __restrict__ b_sparse,
              const float* __restrict__ b_gates,
              const float* __restrict__ alpha,
              float* __restrict__ out)
{
    const int r = blockIdx.x * 256 + threadIdx.x;
    const float4* w4 = reinterpret_cast<const float4*>(ws);

    float l[32];
    #pragma unroll
    for (int j = 0; j < 32; ++j) l[j] = 0.0f;
    #pragma unroll
    for (int gy = 0; gy < DGRP; ++gy)
        #pragma unroll
        for (int q = 0; q < 8; ++q) {
            float4 v = w4[(size_t)(gy * 8 + q) * NROWS + r];
            l[q * 4 + 0] += v.x; l[q * 4 + 1] += v.y;
            l[q * 4 + 2] += v.z; l[q * 4 + 3] += v.w;
        }

    float lc[TT], lsp[TT], g[TT];
    #pragma unroll
    for (int t = 0; t < TT; ++t) {
        lc[t]  = l[t]      + b_cls[t];
        lsp[t] = l[10 + t] + b_sparse[t];
        float lg = l[20 + t] + b_gates[t];
        g[t] = 1.0f / (1.0f + __expf(-lg));
    }
    float m = lc[0];
    #pragma unroll
    for (int t = 1; t < TT; ++t) m = fmaxf(m, lc[t]);
    float esum = 0.0f, gdot = 0.0f;
    #pragma unroll
    for (int t = 0; t < TT; ++t) {
        float e = __expf(lc[t] - m);
        esum += e;
        gdot = fmaf(g[t], e, gdot);
    }
    float v1 = lsp[0], v2 = -1e30f, gv1 = g[0], gv2 = 0.0f;
    #pragma unroll
    for (int t = 1; t < TT; ++t) {
        if (lsp[t] > v1)      { v2 = v1; gv2 = gv1; v1 = lsp[t]; gv1 = g[t]; }
        else if (lsp[t] > v2) { v2 = lsp[t]; gv2 = g[t]; }
    }
    float s1 = 1.0f / (1.0f + __expf(v2 - v1));
    float s2 = 1.0f - s1;
    float a  = 1.0f / (1.0f + __expf(-alpha[0]));
    float sparse_dot = fmaf(gv1, s1, gv2 * s2);
    out[r] = fmaf(a, sparse_dot, (1.0f - a) * (gdot / esum));
}

extern "C" void kernel_launch(void* const* d_in, const int* in_sizes, int n_in,
                              void* d_out, int out_size, void* d_ws, size_t ws_size,
                              hipStream_t stream) {
    const float* x        = (const float*)d_in[0];
    const float* W_cls    = (const float*)d_in[1];
    const float* b_cls    = (const float*)d_in[2];
    const float* W_sparse = (const float*)d_in[3];
    const float* b_sparse = (const float*)d_in[4];
    const float* W_gates  = (const float*)d_in[5];
    const float* b_gates  = (const float*)d_in[6];
    const float* alpha    = (const float*)d_in[7];
    float* out = (float*)d_out;
    float* ws  = (float*)d_ws;   // DGRP*8*NROWS*16 B = 16.8 MB

    dim3 g1(NROWS / RPB, DGRP);   // 64 x 8 = 512 blocks (2/CU residency)
    tgate_k1<<<g1, dim3(BLOCK), 0, stream>>>(x, W_cls, W_sparse, W_gates, ws);

    dim3 g2(NROWS / 256);         // 64 blocks
    tgate_k2<<<g2, dim3(256), 0, stream>>>(ws, b_cls, b_sparse, b_gates, alpha, out);
}

// Round 5
// 228.023 us; speedup vs baseline: 1.0564x; 1.0564x over previous
//
#include <hip/hip_runtime.h>
#include <math.h>
#include <stdint.h>

// tgate_hybrid: B=4,S=4096,DIMS=2048,T=10,K=2.
// R5: MFMA rewrite. C[16384,32] = x[16384,2048] . W[2048,32]
//   (32 = cls0..9 | sparse0..9 | gates0..9 | pad2), split-bf16 3-term
//   (xh*wh + xl*wh + xh*wl) for fp32-grade accuracy on 16x16x32 bf16 MFMA.
// k0: pack W into hi/lo B-fragments (lane-ordered, coalesced).  ~256 KB.
// k1: grid (256 rowtile-blocks x 8 k-slices), 4 waves/block, wave = 16 rows
//     x 256 k. A loaded fp32 straight from global (16 rows x 128 B lines,
//     fully consumed), converted to bf16 hi/lo in regs. acc = 8 VGPRs.
// k2: thread-per-row 8-slice reduction + softmax/top2/sigmoid epilogue.

#define NROWS   16384
#define DIMS_   2048
#define TT      10
#define NCOL    32
#define KSL     8                 // k-slices
#define KSTEPS  (DIMS_ / 32)      // 64 MFMA k-steps total
#define KPS     (KSTEPS / KSL)    // 8 k-steps per slice

typedef __attribute__((ext_vector_type(8))) short short8;
typedef __attribute__((ext_vector_type(4))) float f32x4;

__device__ __forceinline__ unsigned short bf16_rne(float f) {
    unsigned int u = __float_as_uint(f);
    unsigned int r = u + 0x7fffu + ((u >> 16) & 1u);
    return (unsigned short)(r >> 16);
}

// ---- k0: build B fragments. frag[(K0*4 + nt*2 + h)*64 + lane] = short8
//      B-frag layout (16x16x32): n = lane&15, k = (lane>>4)*8 + j.
__global__ __launch_bounds__(256)
void tgate_k0(const float* __restrict__ W_cls,
              const float* __restrict__ W_sparse,
              const float* __restrict__ W_gates,
              unsigned short* __restrict__ frag)
{
    int t = blockIdx.x * 256 + threadIdx.x;    // 8192 threads: (K0, nt, lane)
    int K0   = t >> 7;
    int nt   = (t >> 6) & 1;
    int lane = t & 63;
    int n  = nt * 16 + (lane & 15);
    int kb = K0 * 32 + (lane >> 4) * 8;
    short8 hi, lo;
    #pragma unroll
    for (int j = 0; j < 8; ++j) {
        int k = kb + j;
        float w = 0.0f;
        if (n < 10)      w = W_cls[k * TT + n];
        else if (n < 20) w = W_sparse[k * TT + n - 10];
        else if (n < 30) w = W_gates[k * TT + n - 20];
        unsigned short h = bf16_rne(w);
        float back = __uint_as_float(((unsigned int)h) << 16);
        hi[j] = (short)h;
        lo[j] = (short)bf16_rne(w - back);
    }
    short8* fv = reinterpret_cast<short8*>(frag);
    fv[(K0 * 4 + nt * 2 + 0) * 64 + lane] = hi;
    fv[(K0 * 4 + nt * 2 + 1) * 64 + lane] = lo;
}

// ---- k1: MFMA partial GEMM
__global__ __launch_bounds__(256)
void tgate_k1(const float* __restrict__ x,
              const unsigned short* __restrict__ frag,
              float* __restrict__ part)
{
    const int lane  = threadIdx.x & 63;
    const int wv    = threadIdx.x >> 6;
    const int rt    = blockIdx.x * 4 + wv;     // row-tile 0..1023
    const int row0  = rt * 16;
    const int slice = blockIdx.y;              // 0..7
    const int m     = lane & 15;
    const int quad  = lane >> 4;

    const short8* fv = reinterpret_cast<const short8*>(frag);
    const float*  xrow = x + (size_t)(row0 + m) * DIMS_;

    f32x4 acc0 = {0.f, 0.f, 0.f, 0.f};
    f32x4 acc1 = {0.f, 0.f, 0.f, 0.f};

    #pragma unroll
    for (int ks = 0; ks < KPS; ++ks) {
        const int K0 = slice * KPS + ks;
        const int kb = K0 * 32 + quad * 8;
        float4 a0 = *reinterpret_cast<const float4*>(xrow + kb);
        float4 a1 = *reinterpret_cast<const float4*>(xrow + kb + 4);
        float f[8] = {a0.x, a0.y, a0.z, a0.w, a1.x, a1.y, a1.z, a1.w};
        short8 ah, al;
        #pragma unroll
        for (int j = 0; j < 8; ++j) {
            unsigned short h = bf16_rne(f[j]);
            float back = __uint_as_float(((unsigned int)h) << 16);
            ah[j] = (short)h;
            al[j] = (short)bf16_rne(f[j] - back);
        }
        short8 fh0 = fv[(K0 * 4 + 0) * 64 + lane];
        short8 fl0 = fv[(K0 * 4 + 1) * 64 + lane];
        short8 fh1 = fv[(K0 * 4 + 2) * 64 + lane];
        short8 fl1 = fv[(K0 * 4 + 3) * 64 + lane];
        acc0 = __builtin_amdgcn_mfma_f32_16x16x32_bf16(ah, fh0, acc0, 0, 0, 0);
        acc0 = __builtin_amdgcn_mfma_f32_16x16x32_bf16(al, fh0, acc0, 0, 0, 0);
        acc0 = __builtin_amdgcn_mfma_f32_16x16x32_bf16(ah, fl0, acc0, 0, 0, 0);
        acc1 = __builtin_amdgcn_mfma_f32_16x16x32_bf16(ah, fh1, acc1, 0, 0, 0);
        acc1 = __builtin_amdgcn_mfma_f32_16x16x32_bf16(al, fh1, acc1, 0, 0, 0);
        acc1 = __builtin_amdgcn_mfma_f32_16x16x32_bf16(ah, fl1, acc1, 0, 0, 0);
    }

    // C/D layout (verified m89): col = lane&15, row = (lane>>4)*4 + reg
    #pragma unroll
    for (int r = 0; r < 4; ++r) {
        int row = row0 + quad * 4 + r;
        float* p = part + ((size_t)slice * NROWS + row) * NCOL;
        p[m]      = acc0[r];
        p[m + 16] = acc1[r];
    }
}

// ---- k2: 8-slice reduction + epilogue (validated structure)
__global__ __launch_bounds__(256)
void tgate_k2(const float* __restrict__ part,
              const float* __restrict__ b_cls,
              const float* __restrict__ b_sparse,
              const float* __restrict__ b_gates,
              const float* __restrict__ alpha,
              float* __restrict__ out)
{
    const int r = blockIdx.x * 256 + threadIdx.x;
    const float4* p4 = reinterpret_cast<const float4*>(part);

    float l[32];
    #pragma unroll
    for (int j = 0; j < 32; ++j) l[j] = 0.0f;
    #pragma unroll
    for (int s = 0; s < KSL; ++s) {
        size_t base = ((size_t)s * NROWS + r) * 8;
        #pragma unroll
        for (int q = 0; q < 8; ++q) {
            float4 v = p4[base + q];
            l[q * 4 + 0] += v.x; l[q * 4 + 1] += v.y;
            l[q * 4 + 2] += v.z; l[q * 4 + 3] += v.w;
        }
    }

    float lc[TT], lsp[TT], g[TT];
    #pragma unroll
    for (int t = 0; t < TT; ++t) {
        lc[t]  = l[t]      + b_cls[t];
        lsp[t] = l[10 + t] + b_sparse[t];
        float lg = l[20 + t] + b_gates[t];
        g[t] = 1.0f / (1.0f + __expf(-lg));
    }
    float m = lc[0];
    #pragma unroll
    for (int t = 1; t < TT; ++t) m = fmaxf(m, lc[t]);
    float esum = 0.0f, gdot = 0.0f;
    #pragma unroll
    for (int t = 0; t < TT; ++t) {
        float e = __expf(lc[t] - m);
        esum += e;
        gdot = fmaf(g[t], e, gdot);
    }
    float v1 = lsp[0], v2 = -1e30f, gv1 = g[0], gv2 = 0.0f;
    #pragma unroll
    for (int t = 1; t < TT; ++t) {
        if (lsp[t] > v1)      { v2 = v1; gv2 = gv1; v1 = lsp[t]; gv1 = g[t]; }
        else if (lsp[t] > v2) { v2 = lsp[t]; gv2 = g[t]; }
    }
    float s1 = 1.0f / (1.0f + __expf(v2 - v1));
    float s2 = 1.0f - s1;
    float a  = 1.0f / (1.0f + __expf(-alpha[0]));
    float sparse_dot = fmaf(gv1, s1, gv2 * s2);
    out[r] = fmaf(a, sparse_dot, (1.0f - a) * (gdot / esum));
}

extern "C" void kernel_launch(void* const* d_in, const int* in_sizes, int n_in,
                              void* d_out, int out_size, void* d_ws, size_t ws_size,
                              hipStream_t stream) {
    const float* x        = (const float*)d_in[0];
    const float* W_cls    = (const float*)d_in[1];
    const float* b_cls    = (const float*)d_in[2];
    const float* W_sparse = (const float*)d_in[3];
    const float* b_sparse = (const float*)d_in[4];
    const float* W_gates  = (const float*)d_in[5];
    const float* b_gates  = (const float*)d_in[6];
    const float* alpha    = (const float*)d_in[7];
    float* out = (float*)d_out;

    // ws carve: [0, 256KB) = B fragments; [512KB, 512KB+16.8MB) = partials
    unsigned short* frag = (unsigned short*)d_ws;
    float* part = (float*)((char*)d_ws + (512 << 10));

    tgate_k0<<<dim3(32), dim3(256), 0, stream>>>(W_cls, W_sparse, W_gates, frag);
    tgate_k1<<<dim3(NROWS / 64, KSL), dim3(256), 0, stream>>>(x, frag, part);
    tgate_k2<<<dim3(NROWS / 256), dim3(256), 0, stream>>>(part, b_cls, b_sparse,
                                                          b_gates, alpha, out);
}